// Round 10
// baseline (28.249 us; speedup 1.0000x reference)
//
#include <hip/hip_runtime.h>

#define DEGREE 32
#define DIMS 8
#define NB 32
#define NPOS 65536
#define BLOCK 256
#define ITERS 4
#define GRID  (8192 / ITERS)      // 2048 blocks; tile t = bid + GRID*it

// e_g = exp2(K*(x - g*h)^2), K = -12.5*log2(e), h = 1.01/31.
// Geometric recurrence: s_{g+1}/s_g = q * r^(2g+1) with
//   q = 2^(-2Kh*x) = 2^(QCOEF*x),  r = 2^(K*h^2).
// Pairwise (S = (s_g, s_{g+1}), g even): S_{g+2} = S_g * M_g,
//   M_0 = (q^2*r^4, q^2*r^8),  M_{g+2} = M_g * r^8.
#define SQK    4.24660911f        // sqrt(-K): s_0 = exp2(-(x*SQK)^2)
#define QCOEF  1.17509838f        // -2*K*h
#define R1     0.9868193f         // r
#define R4     0.9483070f         // r^4
#define R8     0.8992862f         // r^8

typedef __attribute__((ext_vector_type(2))) float f32x2;
typedef __attribute__((ext_vector_type(4))) float f32x4;

__global__ __launch_bounds__(BLOCK) void basis_kernel(
    const float* __restrict__ weights,    // (B, DIMS, DEGREE)
    const float* __restrict__ positions,  // (B, N)
    float* __restrict__ out,              // (B, N, DIMS)
    float* __restrict__ out_zero)         // (B, N, DIMS) -> zeros
{
    const int bid  = blockIdx.x;
    const int tid  = threadIdx.x;
    const int wv   = tid >> 6;            // wave id in block
    const int lane = tid & 63;

    __shared__ f32x4 lv[BLOCK * 2];       // 8KB; wave w owns lv[128w .. 128w+128)

    // ---- all position loads upfront: the vmcnt queue is store-free when we
    //      wait on them (waiting on a load behind stores would drain the stores) ----
    float x[ITERS];
    #pragma unroll
    for (int it = 0; it < ITERS; ++it) {
        const int t = bid + GRID * it;
        const int n = ((t & 255) << 8) + tid;
        x[it] = positions[(size_t)(t >> 8) * NPOS + n];
    }

    #pragma unroll 1
    for (int it = 0; it < ITERS; ++it) {
        const int t = bid + GRID * it;    // tile 0..8191
        const int b = t >> 8;
        const size_t tileBase = ((size_t)b * NPOS + ((size_t)(t & 255) << 8)) * DIMS;

        // ---- zero tile first: independent, drains under this tile's compute ----
        {
            f32x4* zblk = reinterpret_cast<f32x4*>(out_zero + tileBase);
            const f32x4 zz = {0.0f, 0.0f, 0.0f, 0.0f};
            zblk[tid]         = zz;
            zblk[tid + BLOCK] = zz;
        }

        const float* __restrict__ wb = weights + b * (DIMS * DEGREE);
        const float xx = x[it];

        // ---- recurrence state ----
        const float u  = xx * SQK;
        const float s0 = __builtin_amdgcn_exp2f(-(u * u));   // e_0
        const float q  = __builtin_amdgcn_exp2f(QCOEF * xx);
        const float q2 = q * q;
        f32x2 S; S.x = s0; S.y = s0 * q * R1;                // (e_0, e_1)
        f32x2 M; M.x = q2 * R4; M.y = q2 * R8;
        const f32x2 R8v = {R8, R8};

        f32x2 acc[DIMS];
        #pragma unroll
        for (int d = 0; d < DIMS; ++d) { acc[d].x = 0.0f; acc[d].y = 0.0f; }

        #pragma unroll 4
        for (int gp = 0; gp < DEGREE / 2; ++gp) {
            const f32x2 e2 = S;
            const int g = gp * 2;
            #pragma unroll
            for (int d = 0; d < DIMS; ++d) {
                // adjacent g contiguous; uniform addr -> s_load_dwordx2
                f32x2 w2 = *reinterpret_cast<const f32x2*>(wb + d * DEGREE + g);
                acc[d] = __builtin_elementwise_fma(e2, w2, acc[d]);  // v_pk_fma_f32
            }
            S *= M;          // v_pk_mul_f32
            M *= R8v;        // v_pk_mul_f32
        }

        // ---- dense result store via per-wave LDS region (barrier-free) ----
        {
            const f32x4 r0 = {acc[0].x + acc[0].y, acc[1].x + acc[1].y,
                              acc[2].x + acc[2].y, acc[3].x + acc[3].y};
            const f32x4 r1 = {acc[4].x + acc[4].y, acc[5].x + acc[5].y,
                              acc[6].x + acc[6].y, acc[7].x + acc[7].y};
            lv[tid * 2]     = r0;      // wave w writes only lv[128w .. 128w+128)
            lv[tid * 2 + 1] = r1;

            // re-read within the same wave's region: intra-wave in-order LDS,
            // no __syncthreads needed
            const int rb = wv * 128;
            f32x4* oblk = reinterpret_cast<f32x4*>(out + tileBase);
            oblk[rb + lane]      = lv[rb + lane];
            oblk[rb + 64 + lane] = lv[rb + 64 + lane];
        }
    }
}

extern "C" void kernel_launch(void* const* d_in, const int* in_sizes, int n_in,
                              void* d_out, int out_size, void* d_ws, size_t ws_size,
                              hipStream_t stream) {
    const float* weights   = (const float*)d_in[0];
    // d_in[1] = weights_std: unused (second output is exactly zeros)
    const float* positions = (const float*)d_in[2];

    float* out      = (float*)d_out;
    float* out_zero = out + (size_t)NB * NPOS * DIMS;

    dim3 grid(GRID);
    dim3 block(BLOCK);
    basis_kernel<<<grid, block, 0, stream>>>(weights, positions, out, out_zero);
}

// Round 11
// 27.017 us; speedup vs baseline: 1.0456x; 1.0456x over previous
//
#include <hip/hip_runtime.h>

#define DEGREE 32
#define DIMS 8
#define NB 32
#define NPOS 65536
#define BLOCK 256

// e_g = exp2(K*(x - g*h)^2), K = -12.5*log2(e), h = 1.01/31.
// Geometric recurrence: s_{g+1}/s_g = q * r^(2g+1) with
//   q = 2^(-2Kh*x) = 2^(QCOEF*x),  r = 2^(K*h^2).
// Pairwise (S = (s_g, s_{g+1}), g even): S_{g+2} = S_g * M_g,
//   M_0 = (q^2*r^4, q^2*r^8),  M_{g+2} = M_g * r^8.
#define SQK    4.24660911f        // sqrt(-K): s_0 = exp2(-(x*SQK)^2)
#define QCOEF  1.17509838f        // -2*K*h
#define R1     0.9868193f         // r
#define R4     0.9483070f         // r^4
#define R8     0.8992862f         // r^8

#define NCOMP 8192   // 32 batches * 256 blocks, 1 position per thread

typedef __attribute__((ext_vector_type(2))) float f32x2;
typedef __attribute__((ext_vector_type(4))) float f32x4;

__global__ __launch_bounds__(BLOCK) void basis_kernel(
    const float* __restrict__ weights,    // (B, DIMS, DEGREE)
    const float* __restrict__ positions,  // (B, N)
    float* __restrict__ out,              // (B, N, DIMS)
    float* __restrict__ out_zero)         // (B, N, DIMS) -> zeros
{
    const int cb  = blockIdx.x;           // 0..NCOMP-1
    const int b   = cb >> 8;
    const int tid = threadIdx.x;
    const int n   = ((cb & 255) << 8) + tid;

    const float* __restrict__ wb = weights + b * (DIMS * DEGREE);
    const float x = positions[(size_t)b * NPOS + n];   // oldest vmem op: its wait
                                                       // does not drain later stores
    // ---- own zero tile (mirror offset): independent, drains under compute ----
    const size_t tileBase = ((size_t)b * NPOS + ((size_t)(cb & 255) << 8)) * DIMS;
    {
        f32x4* zblk = reinterpret_cast<f32x4*>(out_zero + tileBase);
        const f32x4 zz = {0.0f, 0.0f, 0.0f, 0.0f};
        zblk[tid]         = zz;
        zblk[tid + BLOCK] = zz;
    }

    // ---- recurrence state ----
    const float u  = x * SQK;
    const float s0 = __builtin_amdgcn_exp2f(-(u * u));   // e_0
    const float q  = __builtin_amdgcn_exp2f(QCOEF * x);
    const float q2 = q * q;
    f32x2 S; S.x = s0; S.y = s0 * q * R1;                // (e_0, e_1)
    f32x2 M; M.x = q2 * R4; M.y = q2 * R8;
    const f32x2 R8v = {R8, R8};

    f32x2 acc[DIMS];
    #pragma unroll
    for (int d = 0; d < DIMS; ++d) { acc[d].x = 0.0f; acc[d].y = 0.0f; }

    #pragma unroll 4
    for (int gp = 0; gp < DEGREE / 2; ++gp) {
        const f32x2 e2 = S;
        const int g = gp * 2;
        #pragma unroll
        for (int d = 0; d < DIMS; ++d) {
            // adjacent g contiguous in memory; uniform addr -> s_load_dwordx2
            f32x2 w2 = *reinterpret_cast<const f32x2*>(wb + d * DEGREE + g);
            acc[d] = __builtin_elementwise_fma(e2, w2, acc[d]);  // v_pk_fma_f32
        }
        S *= M;          // v_pk_mul_f32: advance (e_g, e_{g+1})
        M *= R8v;        // v_pk_mul_f32: advance step ratio
    }

    // ---- direct result stores (two dwordx4; lines merge in write-back L2) ----
    const f32x4 r0 = {acc[0].x + acc[0].y, acc[1].x + acc[1].y,
                      acc[2].x + acc[2].y, acc[3].x + acc[3].y};
    const f32x4 r1 = {acc[4].x + acc[4].y, acc[5].x + acc[5].y,
                      acc[6].x + acc[6].y, acc[7].x + acc[7].y};
    f32x4* o = reinterpret_cast<f32x4*>(out + (size_t)(((size_t)b * NPOS + n) * DIMS));
    o[0] = r0;
    o[1] = r1;
}

extern "C" void kernel_launch(void* const* d_in, const int* in_sizes, int n_in,
                              void* d_out, int out_size, void* d_ws, size_t ws_size,
                              hipStream_t stream) {
    const float* weights   = (const float*)d_in[0];
    // d_in[1] = weights_std: unused (second output is exactly zeros)
    const float* positions = (const float*)d_in[2];

    float* out      = (float*)d_out;
    float* out_zero = out + (size_t)NB * NPOS * DIMS;

    dim3 grid(NCOMP);
    dim3 block(BLOCK);
    basis_kernel<<<grid, block, 0, stream>>>(weights, positions, out, out_zero);
}

// Round 12
// 26.628 us; speedup vs baseline: 1.0609x; 1.0146x over previous
//
#include <hip/hip_runtime.h>

#define DEGREE 32
#define DIMS 8
#define NB 32
#define NPOS 65536
#define BLOCK 256

// e_g = exp2(K*(x - g*h)^2), K = -12.5*log2(e), h = 1.01/31.
// Geometric recurrence: s_{g+1}/s_g = q * r^(2g+1) with
//   q = 2^(-2Kh*x) = 2^(QCOEF*x),  r = 2^(K*h^2).
// Pairwise (S = (s_g, s_{g+1}), g even): S_{g+2} = S_g * M_g,
//   M_0 = (q^2*r^4, q^2*r^8),  M_{g+2} = M_g * r^8.
#define SQK    4.24660911f        // sqrt(-K): s_0 = exp2(-(x*SQK)^2)
#define QCOEF  1.17509838f        // -2*K*h
#define R1     0.9868193f         // r
#define R4     0.9483070f         // r^4
#define R8     0.8992862f         // r^8

#define NCOMP 8192   // 32 batches * 256 blocks, 1 position per thread

typedef __attribute__((ext_vector_type(2))) float f32x2;
typedef __attribute__((ext_vector_type(4))) float f32x4;

__global__ __launch_bounds__(BLOCK) void basis_kernel(
    const float* __restrict__ weights,    // (B, DIMS, DEGREE)
    const float* __restrict__ positions,  // (B, N)
    float* __restrict__ out,              // (B, N, DIMS)
    float* __restrict__ out_zero)         // (B, N, DIMS) -> zeros
{
    const int cb   = blockIdx.x;          // 0..NCOMP-1
    const int b    = cb >> 8;
    const int tid  = threadIdx.x;
    const int wv   = tid >> 6;            // wave id in block
    const int lane = tid & 63;
    const int n    = ((cb & 255) << 8) + tid;

    __shared__ f32x4 lv[BLOCK * 2];       // 8KB; wave w owns lv[128w .. 128w+128)

    const float* __restrict__ wb = weights + b * (DIMS * DEGREE);
    const float x = positions[(size_t)b * NPOS + n];   // oldest vmem op: its wait
                                                       // does not drain later stores
    // ---- own zero tile (mirror offset): independent, drains under compute ----
    const size_t tileBase = ((size_t)b * NPOS + ((size_t)(cb & 255) << 8)) * DIMS;
    {
        f32x4* zblk = reinterpret_cast<f32x4*>(out_zero + tileBase);
        const f32x4 zz = {0.0f, 0.0f, 0.0f, 0.0f};
        zblk[tid]         = zz;
        zblk[tid + BLOCK] = zz;
    }

    // ---- recurrence state ----
    const float u  = x * SQK;
    const float s0 = __builtin_amdgcn_exp2f(-(u * u));   // e_0
    const float q  = __builtin_amdgcn_exp2f(QCOEF * x);
    const float q2 = q * q;
    f32x2 S; S.x = s0; S.y = s0 * q * R1;                // (e_0, e_1)
    f32x2 M; M.x = q2 * R4; M.y = q2 * R8;
    const f32x2 R8v = {R8, R8};

    f32x2 acc[DIMS];
    #pragma unroll
    for (int d = 0; d < DIMS; ++d) { acc[d].x = 0.0f; acc[d].y = 0.0f; }

    #pragma unroll 4
    for (int gp = 0; gp < DEGREE / 2; ++gp) {
        const f32x2 e2 = S;
        const int g = gp * 2;
        #pragma unroll
        for (int d = 0; d < DIMS; ++d) {
            // adjacent g contiguous in memory; uniform addr -> s_load_dwordx2
            f32x2 w2 = *reinterpret_cast<const f32x2*>(wb + d * DEGREE + g);
            acc[d] = __builtin_elementwise_fma(e2, w2, acc[d]);  // v_pk_fma_f32
        }
        S *= M;          // v_pk_mul_f32: advance (e_g, e_{g+1})
        M *= R8v;        // v_pk_mul_f32: advance step ratio
    }

    // ---- dense result store via per-wave LDS region (barrier-free) ----
    {
        const f32x4 r0 = {acc[0].x + acc[0].y, acc[1].x + acc[1].y,
                          acc[2].x + acc[2].y, acc[3].x + acc[3].y};
        const f32x4 r1 = {acc[4].x + acc[4].y, acc[5].x + acc[5].y,
                          acc[6].x + acc[6].y, acc[7].x + acc[7].y};
        lv[tid * 2]     = r0;      // wave w writes only lv[128w .. 128w+128)
        lv[tid * 2 + 1] = r1;

        // re-read within the same wave's region: intra-wave in-order LDS,
        // no __syncthreads needed
        const int rb = wv * 128;
        f32x4* oblk = reinterpret_cast<f32x4*>(out + tileBase);
        oblk[rb + lane]      = lv[rb + lane];
        oblk[rb + 64 + lane] = lv[rb + 64 + lane];
    }
}

extern "C" void kernel_launch(void* const* d_in, const int* in_sizes, int n_in,
                              void* d_out, int out_size, void* d_ws, size_t ws_size,
                              hipStream_t stream) {
    const float* weights   = (const float*)d_in[0];
    // d_in[1] = weights_std: unused (second output is exactly zeros)
    const float* positions = (const float*)d_in[2];

    float* out      = (float*)d_out;
    float* out_zero = out + (size_t)NB * NPOS * DIMS;

    dim3 grid(NCOMP);
    dim3 block(BLOCK);
    basis_kernel<<<grid, block, 0, stream>>>(weights, positions, out, out_zero);
}